// Round 8
// baseline (30767.548 us; speedup 1.0000x reference)
//
#include <hip/hip_runtime.h>
#include <cstdint>
#include <cmath>

#define RNG_VARIANT 1

#define NROWS 4096
#define HIDN 512
#define VOC 32
#define TSTEPS 64
#define PAD_TOK 0
#define BOS_TOK 1
#define EOS_TOK 2

#define BK 32
#define BM 128
#define JJT 32   // gate-local columns per block; GEMM N-tile = 4*JJT = 128

typedef const __attribute__((address_space(1))) unsigned int* gptr_t;
typedef __attribute__((address_space(3))) unsigned int* lptr_t;

// ---------------- threefry2x32 (JAX-compatible, 20 rounds) ----------------
__host__ __device__ inline void tf2x32(unsigned k0, unsigned k1, unsigned x0, unsigned x1,
                                       unsigned& o0, unsigned& o1) {
  unsigned ks0 = k0, ks1 = k1, ks2 = k0 ^ k1 ^ 0x1BD11BDAu;
  unsigned X0 = x0 + ks0, X1 = x1 + ks1;
  const unsigned R[5][4] = {{13,15,26,6},{17,29,16,24},{13,15,26,6},{17,29,16,24},{13,15,26,6}};
  unsigned inj0[5], inj1[5];
  inj0[0] = ks1; inj1[0] = ks2;
  inj0[1] = ks2; inj1[1] = ks0;
  inj0[2] = ks0; inj1[2] = ks1;
  inj0[3] = ks1; inj1[3] = ks2;
  inj0[4] = ks2; inj1[4] = ks0;
#pragma unroll
  for (int i = 0; i < 5; ++i) {
#pragma unroll
    for (int j = 0; j < 4; ++j) {
      X0 += X1;
      unsigned r = R[i][j];
      X1 = (X1 << r) | (X1 >> (32 - r));
      X1 ^= X0;
    }
    X0 += inj0[i];
    X1 += inj1[i] + (unsigned)(i + 1);
  }
  o0 = X0; o1 = X1;
}

// ---------------- fused GEMM (A@B^T over NPARTS) + LSTM gate activation ----------------
// LDS tiles ROW-MAJOR [128 rows][32 k-floats]; global_load_lds width-16 coalesced
// (1 instr = 8 rows x 128B). XOR chunk swizzle (involution on source + read) keeps
// ds_read_b128 conflict-free (verified: SQ_LDS_BANK_CONFLICT == 0).
// Inner kg loop is software-pipelined with TWO register fragment sets (kg+1 loads
// issue under kg's FMA burst). Requires ~200 VGPR -> __launch_bounds__(256,1);
// grid (512 blocks = 2 blocks/CU) caps occupancy at 2 waves/SIMD regardless, so
// the extra VGPR is free. FMA order (k ascending, parts sequential) unchanged.
template<int NPARTS, bool LAYER0>
__global__ __launch_bounds__(256, 1) void lstm_fused(
    const float* __restrict__ A0, const float* __restrict__ B0,
    const float* __restrict__ A1, const float* __restrict__ B1,
    const float* __restrict__ extra,   // LAYER0: EW0i[32][2048] interleaved; else bias1i[2048]
    const int* __restrict__ tokv,
    float* __restrict__ h, float* __restrict__ c)
{
  __shared__ float As[2][BM * BK];
  __shared__ float Bs[2][BM * BK];
  const int tid = threadIdx.x;
  const int lane = tid & 63;
  const int w = tid >> 6;                 // wave 0..3
  const int wr = w >> 1, wc = w & 1;      // wave tile: 64 rows x 64 GEMM cols
  const int ty = lane >> 3, tx = lane & 7;
  const int m0 = blockIdx.y * BM;
  const int c0 = blockIdx.x * JJT;

  float acc[8][8];
#pragma unroll
  for (int i = 0; i < 8; ++i)
#pragma unroll
    for (int j = 0; j < 8; ++j) acc[i][j] = 0.f;

  const int NT = NPARTS * (HIDN / BK);
  const int g8 = lane >> 3;               // 0..7 row-within-group
  const int ch = lane & 7;                // 0..7 chunk slot

  auto STAGE = [&](int tt, int sel) {
    const float* A = A0;
    const float* B = B0;
    if (NPARTS == 2 && (tt >> 4)) { A = A1; B = B1; }
    const int kb = (tt & 15) * BK;
    float* dA = &As[sel][0];
    float* dB = &Bs[sel][0];
#pragma unroll
    for (int i = 0; i < 4; ++i) {
      const int rbase = w * 32 + i * 8;         // aligned 8-row group
      const int swz = (rbase >> 3) & 7;         // uniform within the group
      const int mA = rbase + g8;
      const float* sA = A + (size_t)(m0 + mA) * HIDN + kb + ((ch ^ swz) << 2);
      __builtin_amdgcn_global_load_lds((gptr_t)sA, (lptr_t)(dA + rbase * BK), 16, 0, 0);
      const int mB = rbase + g8;                 // local jq row
      const int grB = (mB & 3) * HIDN + c0 + (mB >> 2);
      const float* sB = B + (size_t)grB * HIDN + kb + ((ch ^ swz) << 2);
      __builtin_amdgcn_global_load_lds((gptr_t)sB, (lptr_t)(dB + rbase * BK), 16, 0, 0);
    }
  };

  STAGE(0, 0);
  __syncthreads();                        // vmcnt(0) + barrier: tile 0 landed
  int sel = 0;
  const int aRow = wr * 64 + ty * 8;
  const int bRow = wc * 64 + tx * 8;
  for (int tt = 0; tt < NT; ++tt) {
    if (tt + 1 < NT) STAGE(tt + 1, sel ^ 1);
    const float* As_ = &As[sel][0];
    const float* Bs_ = &Bs[sel][0];

    float4 av[2][8], bv[2][8];
    // pipelined kg loop: sets indexed by kg&1 (compile-time after full unroll)
#pragma unroll
    for (int i = 0; i < 8; ++i)
      av[0][i] = *(const float4*)(As_ + (aRow + i) * BK + ((0 ^ ty) << 2));
#pragma unroll
    for (int j = 0; j < 8; ++j)
      bv[0][j] = *(const float4*)(Bs_ + (bRow + j) * BK + ((0 ^ tx) << 2));
#pragma unroll
    for (int kg = 0; kg < 8; ++kg) {
      const int cur = kg & 1, nxt = cur ^ 1;
      if (kg < 7) {
#pragma unroll
        for (int i = 0; i < 8; ++i)
          av[nxt][i] = *(const float4*)(As_ + (aRow + i) * BK + (((kg + 1) ^ ty) << 2));
#pragma unroll
        for (int j = 0; j < 8; ++j)
          bv[nxt][j] = *(const float4*)(Bs_ + (bRow + j) * BK + (((kg + 1) ^ tx) << 2));
      }
#pragma unroll
      for (int i = 0; i < 8; ++i)
#pragma unroll
        for (int j = 0; j < 8; ++j)
          acc[i][j] = fmaf(av[cur][i].x, bv[cur][j].x, acc[i][j]);
#pragma unroll
      for (int i = 0; i < 8; ++i)
#pragma unroll
        for (int j = 0; j < 8; ++j)
          acc[i][j] = fmaf(av[cur][i].y, bv[cur][j].y, acc[i][j]);
#pragma unroll
      for (int i = 0; i < 8; ++i)
#pragma unroll
        for (int j = 0; j < 8; ++j)
          acc[i][j] = fmaf(av[cur][i].z, bv[cur][j].z, acc[i][j]);
#pragma unroll
      for (int i = 0; i < 8; ++i)
#pragma unroll
        for (int j = 0; j < 8; ++j)
          acc[i][j] = fmaf(av[cur][i].w, bv[cur][j].w, acc[i][j]);
    }
    __syncthreads();                      // drains prefetch loads + publishes buffer
    sel ^= 1;
  }

  // -------- epilogue: gate nonlinearity + state update --------
  const int jjl = wc * 16 + tx * 2;       // gate-local column pair base (block-local)
  const size_t colb = (size_t)(c0 + jjl);
  float e[8];
  if (!LAYER0) {
    float4 e0 = *(const float4*)(extra + colb * 4);
    float4 e1 = *(const float4*)(extra + colb * 4 + 4);
    e[0] = e0.x; e[1] = e0.y; e[2] = e0.z; e[3] = e0.w;
    e[4] = e1.x; e[5] = e1.y; e[6] = e1.z; e[7] = e1.w;
  }
#pragma unroll
  for (int i = 0; i < 8; ++i) {
    const int n = m0 + wr * 64 + ty * 8 + i;
    if (LAYER0) {
      const int tk = tokv[n];
      const float* ex = extra + (size_t)tk * 2048 + colb * 4;
      float4 e0 = *(const float4*)(ex);
      float4 e1 = *(const float4*)(ex + 4);
      e[0] = e0.x; e[1] = e0.y; e[2] = e0.z; e[3] = e0.w;
      e[4] = e1.x; e[5] = e1.y; e[6] = e1.z; e[7] = e1.w;
    }
    float gi0 = acc[i][0] + e[0], gf0 = acc[i][1] + e[1];
    float gg0 = acc[i][2] + e[2], go0 = acc[i][3] + e[3];
    float gi1 = acc[i][4] + e[4], gf1 = acc[i][5] + e[5];
    float gg1 = acc[i][6] + e[6], go1 = acc[i][7] + e[7];
    const size_t idx = (size_t)n * HIDN + colb;
    float2 cold = *(const float2*)(c + idx);
    float si0 = 1.f / (1.f + expf(-gi0));
    float sf0 = 1.f / (1.f + expf(-gf0));
    float tg0 = tanhf(gg0);
    float so0 = 1.f / (1.f + expf(-go0));
    float cn0 = sf0 * cold.x + si0 * tg0;
    float hn0 = so0 * tanhf(cn0);
    float si1 = 1.f / (1.f + expf(-gi1));
    float sf1 = 1.f / (1.f + expf(-gf1));
    float tg1 = tanhf(gg1);
    float so1 = 1.f / (1.f + expf(-go1));
    float cn1 = sf1 * cold.y + si1 * tg1;
    float hn1 = so1 * tanhf(cn1);
    *(float2*)(c + idx) = make_float2(cn0, cn1);
    *(float2*)(h + idx) = make_float2(hn0, hn1);
  }
}

// ---------------- EW0i[v][jj*4+q] = (emb[v] @ W_ih0^T)[q*512+jj] + b_ih0 + b_hh0 ----------------
__global__ void build_ew0(const float* __restrict__ emb, const float* __restrict__ W_ih0,
                          const float* __restrict__ b_ih0, const float* __restrict__ b_hh0,
                          float* __restrict__ EW0i)
{
  int idx = blockIdx.x * 256 + threadIdx.x;  // 32*2048
  int vv = idx >> 11, j = idx & 2047;        // j = gate-major index (q*512 + jj)
  float s = b_ih0[j] + b_hh0[j];
#pragma unroll
  for (int e = 0; e < 32; ++e)
    s = fmaf(emb[vv * 32 + e], W_ih0[(size_t)j * 32 + e], s);
  EW0i[(size_t)vv * 2048 + (size_t)(j & 511) * 4 + (j >> 9)] = s;
}

__global__ void build_bias1i(const float* __restrict__ a, const float* __restrict__ b,
                             float* __restrict__ o) {
  int j = blockIdx.x * 256 + threadIdx.x;    // 0..2047 gate-major
  o[(size_t)(j & 511) * 4 + (j >> 9)] = a[j] + b[j];
}

__global__ void init_state(const int* __restrict__ prevs, int* __restrict__ tok,
                           int* __restrict__ is_end, int* __restrict__ lengths,
                           int* __restrict__ out)
{
  int n = blockIdx.x * 256 + threadIdx.x;
  if (n < NROWS) {
    int p = prevs[n];
    tok[n] = p;
    is_end[n] = (p == EOS_TOK) ? 1 : 0;
    lengths[n] = 0;
    out[(size_t)n * (TSTEPS + 1)] = p;
  }
}

// ---------------- logits + gumbel + argmax + token/state update (1 wave / row) ----------------
__global__ __launch_bounds__(64) void sample_step(
    const float* __restrict__ h1, const float* __restrict__ W_out,
    const float* __restrict__ b_out,
    int* __restrict__ tok, int* __restrict__ is_end, int* __restrict__ lengths,
    int* __restrict__ out, unsigned key0, unsigned key1, int t, int last)
{
  __shared__ float hrow[HIDN];
  const int n = blockIdx.x;
  const int lane = threadIdx.x;
  {
    const float4* src = reinterpret_cast<const float4*>(h1 + (size_t)n * HIDN);
    float4* dst = reinterpret_cast<float4*>(hrow);
    dst[lane] = src[lane];
    dst[lane + 64] = src[lane + 64];
  }
  __syncthreads();
  const int v = lane & 31, half = lane >> 5;
  const float* wp = W_out + (size_t)v * HIDN + half * 256;
  const float* hh = hrow + half * 256;
  float dot = 0.f;
#pragma unroll
  for (int k = 0; k < 256; k += 4) {
    float4 wv = *reinterpret_cast<const float4*>(wp + k);
    float4 hv = *reinterpret_cast<const float4*>(hh + k);
    dot = fmaf(wv.x, hv.x, dot);
    dot = fmaf(wv.y, hv.y, dot);
    dot = fmaf(wv.z, hv.z, dot);
    dot = fmaf(wv.w, hv.w, dot);
  }
  dot += __shfl_xor(dot, 32);
  const float logit = dot + b_out[v];

  const unsigned iflat = (unsigned)(n * 32 + v);
  unsigned r0, r1, bits;
#if RNG_VARIANT == 1
  tf2x32(key0, key1, 0u, iflat, r0, r1);
  bits = r0 ^ r1;
#elif RNG_VARIANT == 2
  if (iflat < 65536u) { tf2x32(key0, key1, iflat, iflat + 65536u, r0, r1); bits = r0; }
  else                { tf2x32(key0, key1, iflat - 65536u, iflat, r0, r1); bits = r1; }
#else
  tf2x32(key0, key1, 0u, iflat, r0, r1);
  bits = r1;
#endif
  float f = __uint_as_float((bits >> 9) | 0x3f800000u) - 1.0f;
  float u = fmaxf(f, 1.1754943508222875e-38f);
  float t1 = -(float)log((double)u);
  float g  = -(float)log((double)t1);
  float s = g + logit;

  float bs = s; int bi = v;
#pragma unroll
  for (int off = 16; off >= 1; off >>= 1) {
    float os = __shfl_xor(bs, off);
    int   oi = __shfl_xor(bi, off);
    if (os > bs || (os == bs && oi < bi)) { bs = os; bi = oi; }
  }
  if (lane == 0) {
    const int oe  = is_end[n];
    const int cur = oe ? PAD_TOK : bi;
    const int len = lengths[n] + (oe ? 0 : 1);
    lengths[n] = len;
    is_end[n] = (oe || (cur == EOS_TOK)) ? 1 : 0;
    tok[n] = cur;
    out[(size_t)n * (TSTEPS + 1) + t + 1] = cur;
    if (last) out[(size_t)NROWS * (TSTEPS + 1) + n] = len + 1;
  }
}

// ---------------- host ----------------
extern "C" void kernel_launch(void* const* d_in, const int* in_sizes, int n_in,
                              void* d_out, int out_size, void* d_ws, size_t ws_size,
                              hipStream_t stream)
{
  const int*   prevs = (const int*)d_in[0];
  const float* emb   = (const float*)d_in[1];
  const float* W_ih0 = (const float*)d_in[2];
  const float* W_hh0 = (const float*)d_in[3];
  const float* b_ih0 = (const float*)d_in[4];
  const float* b_hh0 = (const float*)d_in[5];
  const float* W_ih1 = (const float*)d_in[6];
  const float* W_hh1 = (const float*)d_in[7];
  const float* b_ih1 = (const float*)d_in[8];
  const float* b_hh1 = (const float*)d_in[9];
  const float* W_out = (const float*)d_in[10];
  const float* b_out = (const float*)d_in[11];

  const size_t S = (size_t)NROWS * HIDN;
  float* h0a   = (float*)d_ws;      // zeroed (t=0 read)
  float* h1a   = h0a + S;           // zeroed
  float* cl0   = h1a + S;           // zeroed
  float* cl1   = cl0 + S;           // zeroed
  float* h0b   = cl1 + S;
  float* h1b   = h0b + S;
  float* EW0i  = h1b + S;           // 32*2048 interleaved
  float* bias1i = EW0i + (size_t)VOC * 2048;  // 2048 interleaved
  int* tok     = (int*)(bias1i + 2048);
  int* is_end  = tok + NROWS;
  int* lengths = is_end + NROWS;
  int* outp    = (int*)d_out;

  hipMemsetAsync(h0a, 0, 4 * S * sizeof(float), stream);
  init_state<<<NROWS / 256, 256, 0, stream>>>(prevs, tok, is_end, lengths, outp);
  build_ew0<<<VOC * 2048 / 256, 256, 0, stream>>>(emb, W_ih0, b_ih0, b_hh0, EW0i);
  build_bias1i<<<2048 / 256, 256, 0, stream>>>(b_ih1, b_hh1, bias1i);

  unsigned keys[TSTEPS][2];
  for (int t = 0; t < TSTEPS; ++t) {
    unsigned o0, o1;
    tf2x32(0u, 7u, 0u, (unsigned)t, o0, o1);
    keys[t][0] = o0; keys[t][1] = o1;
  }

  dim3 ggrid(HIDN / JJT, NROWS / BM);   // (16, 32) = 512 blocks
  for (int t = 0; t < TSTEPS; ++t) {
    float* h0rd = (t & 1) ? h0b : h0a;
    float* h0wr = (t & 1) ? h0a : h0b;
    float* h1rd = (t & 1) ? h1b : h1a;
    float* h1wr = (t & 1) ? h1a : h1b;
    lstm_fused<1, true><<<ggrid, 256, 0, stream>>>(
        h0rd, W_hh0, nullptr, nullptr, EW0i, tok, h0wr, cl0);
    lstm_fused<2, false><<<ggrid, 256, 0, stream>>>(
        h0wr, W_ih1, h1rd, W_hh1, bias1i, nullptr, h1wr, cl1);
    sample_step<<<NROWS, 64, 0, stream>>>(h1wr, W_out, b_out, tok, is_end, lengths, outp,
                                          keys[t][0], keys[t][1], t, t == TSTEPS - 1);
  }
}

// Round 11
// 21315.691 us; speedup vs baseline: 1.4434x; 1.4434x over previous
//
#include <hip/hip_runtime.h>
#include <cstdint>
#include <cmath>

#define RNG_VARIANT 1

#define NROWS 4096
#define HIDN 512
#define VOC 32
#define TSTEPS 64
#define PAD_TOK 0
#define BOS_TOK 1
#define EOS_TOK 2

#define BK 32
#define BM 128
#define JJT 32   // gate-local columns per block; GEMM N-tile = 4*JJT = 128

typedef const __attribute__((address_space(1))) unsigned int* gptr_t;
typedef __attribute__((address_space(3))) unsigned int* lptr_t;

// ---------------- threefry2x32 (JAX-compatible, 20 rounds) ----------------
__host__ __device__ inline void tf2x32(unsigned k0, unsigned k1, unsigned x0, unsigned x1,
                                       unsigned& o0, unsigned& o1) {
  unsigned ks0 = k0, ks1 = k1, ks2 = k0 ^ k1 ^ 0x1BD11BDAu;
  unsigned X0 = x0 + ks0, X1 = x1 + ks1;
  const unsigned R[5][4] = {{13,15,26,6},{17,29,16,24},{13,15,26,6},{17,29,16,24},{13,15,26,6}};
  unsigned inj0[5], inj1[5];
  inj0[0] = ks1; inj1[0] = ks2;
  inj0[1] = ks2; inj1[1] = ks0;
  inj0[2] = ks0; inj1[2] = ks1;
  inj0[3] = ks1; inj1[3] = ks2;
  inj0[4] = ks2; inj1[4] = ks0;
#pragma unroll
  for (int i = 0; i < 5; ++i) {
#pragma unroll
    for (int j = 0; j < 4; ++j) {
      X0 += X1;
      unsigned r = R[i][j];
      X1 = (X1 << r) | (X1 >> (32 - r));
      X1 ^= X0;
    }
    X0 += inj0[i];
    X1 += inj1[i] + (unsigned)(i + 1);
  }
  o0 = X0; o1 = X1;
}

// ---------------- fused GEMM (A@B^T over NPARTS) + LSTM gate activation ----------------
// Round-5 measured structure (283us L1, VALUBusy 80%, 0 bank conflicts) + ACTIVE-ROW
// COMPACTION: A rows gathered via list[t] (per-lane global_load_lds source = free
// gather); blocks with m0 >= n_active exit before any barrier; pad slots clamp to
// row 0 for staging and are masked in the epilogue. Row arithmetic is keyed by the
// true row index -> values bit-identical regardless of list order.
// NOTE: do NOT explicitly pipeline the kg loop (round-8 A/B: 283->330us regression).
template<int NPARTS, bool LAYER0>
__global__ __launch_bounds__(256, 2) void lstm_fused(
    const float* __restrict__ A0, const float* __restrict__ B0,
    const float* __restrict__ A1, const float* __restrict__ B1,
    const float* __restrict__ extra,   // LAYER0: EW0i[32][2048] interleaved; else bias1i[2048]
    const int* __restrict__ tokv,
    const int* __restrict__ list, const int* __restrict__ cnt, int t,
    float* __restrict__ h, float* __restrict__ c)
{
  const int nact = cnt[t];
  const int m0 = blockIdx.y * BM;
  if (m0 >= nact) return;               // whole block exits together, pre-barrier

  __shared__ float As[2][BM * BK];
  __shared__ float Bs[2][BM * BK];
  const int tid = threadIdx.x;
  const int lane = tid & 63;
  const int w = tid >> 6;                 // wave 0..3
  const int wr = w >> 1, wc = w & 1;      // wave tile: 64 rows x 64 GEMM cols
  const int ty = lane >> 3, tx = lane & 7;
  const int c0 = blockIdx.x * JJT;
  const int toff = t * NROWS;

  const int g8 = lane >> 3;               // 0..7 row-within-group
  const int ch = lane & 7;                // 0..7 chunk slot

  // gathered A-rows for this thread's 4 stage groups (loop-invariant)
  int ra[4];
#pragma unroll
  for (int i = 0; i < 4; ++i) {
    const int slot = m0 + w * 32 + i * 8 + g8;
    ra[i] = (slot < nact) ? list[toff + slot] : 0;   // clamp pad slots to row 0 (safe addr)
  }

  float acc[8][8];
#pragma unroll
  for (int i = 0; i < 8; ++i)
#pragma unroll
    for (int j = 0; j < 8; ++j) acc[i][j] = 0.f;

  const int NT = NPARTS * (HIDN / BK);

  auto STAGE = [&](int tt, int sel) {
    const float* A = A0;
    const float* B = B0;
    if (NPARTS == 2 && (tt >> 4)) { A = A1; B = B1; }
    const int kb = (tt & 15) * BK;
    float* dA = &As[sel][0];
    float* dB = &Bs[sel][0];
#pragma unroll
    for (int i = 0; i < 4; ++i) {
      const int rbase = w * 32 + i * 8;         // aligned 8-row group
      const int swz = (rbase >> 3) & 7;         // uniform within the group
      const float* sA = A + (size_t)ra[i] * HIDN + kb + ((ch ^ swz) << 2);
      __builtin_amdgcn_global_load_lds((gptr_t)sA, (lptr_t)(dA + rbase * BK), 16, 0, 0);
      const int mB = rbase + g8;                 // local jq row
      const int grB = (mB & 3) * HIDN + c0 + (mB >> 2);
      const float* sB = B + (size_t)grB * HIDN + kb + ((ch ^ swz) << 2);
      __builtin_amdgcn_global_load_lds((gptr_t)sB, (lptr_t)(dB + rbase * BK), 16, 0, 0);
    }
  };

  STAGE(0, 0);
  __syncthreads();                        // vmcnt(0) + barrier: tile 0 landed
  int sel = 0;
  const int aRow = wr * 64 + ty * 8;
  const int bRow = wc * 64 + tx * 8;
  for (int tt = 0; tt < NT; ++tt) {
    if (tt + 1 < NT) STAGE(tt + 1, sel ^ 1);
    const float* As_ = &As[sel][0];
    const float* Bs_ = &Bs[sel][0];
#pragma unroll
    for (int kg = 0; kg < 8; ++kg) {
      float4 av[8], bv[8];
#pragma unroll
      for (int i = 0; i < 8; ++i)
        av[i] = *(const float4*)(As_ + (aRow + i) * BK + ((kg ^ ty) << 2));
#pragma unroll
      for (int j = 0; j < 8; ++j)
        bv[j] = *(const float4*)(Bs_ + (bRow + j) * BK + ((kg ^ tx) << 2));
#pragma unroll
      for (int i = 0; i < 8; ++i)
#pragma unroll
        for (int j = 0; j < 8; ++j)
          acc[i][j] = fmaf(av[i].x, bv[j].x, acc[i][j]);
#pragma unroll
      for (int i = 0; i < 8; ++i)
#pragma unroll
        for (int j = 0; j < 8; ++j)
          acc[i][j] = fmaf(av[i].y, bv[j].y, acc[i][j]);
#pragma unroll
      for (int i = 0; i < 8; ++i)
#pragma unroll
        for (int j = 0; j < 8; ++j)
          acc[i][j] = fmaf(av[i].z, bv[j].z, acc[i][j]);
#pragma unroll
      for (int i = 0; i < 8; ++i)
#pragma unroll
        for (int j = 0; j < 8; ++j)
          acc[i][j] = fmaf(av[i].w, bv[j].w, acc[i][j]);
    }
    __syncthreads();                      // drains prefetch loads + publishes buffer
    sel ^= 1;
  }

  // -------- epilogue: gate nonlinearity + state update (masked to live slots) --------
  const int jjl = wc * 16 + tx * 2;       // gate-local column pair base (block-local)
  const size_t colb = (size_t)(c0 + jjl);
  float e[8];
  if (!LAYER0) {
    float4 e0 = *(const float4*)(extra + colb * 4);
    float4 e1 = *(const float4*)(extra + colb * 4 + 4);
    e[0] = e0.x; e[1] = e0.y; e[2] = e0.z; e[3] = e0.w;
    e[4] = e1.x; e[5] = e1.y; e[6] = e1.z; e[7] = e1.w;
  }
#pragma unroll
  for (int i = 0; i < 8; ++i) {
    const int slot = m0 + wr * 64 + ty * 8 + i;
    if (slot >= nact) continue;
    const int n = list[toff + slot];
    if (LAYER0) {
      const int tk = tokv[n];
      const float* ex = extra + (size_t)tk * 2048 + colb * 4;
      float4 e0 = *(const float4*)(ex);
      float4 e1 = *(const float4*)(ex + 4);
      e[0] = e0.x; e[1] = e0.y; e[2] = e0.z; e[3] = e0.w;
      e[4] = e1.x; e[5] = e1.y; e[6] = e1.z; e[7] = e1.w;
    }
    float gi0 = acc[i][0] + e[0], gf0 = acc[i][1] + e[1];
    float gg0 = acc[i][2] + e[2], go0 = acc[i][3] + e[3];
    float gi1 = acc[i][4] + e[4], gf1 = acc[i][5] + e[5];
    float gg1 = acc[i][6] + e[6], go1 = acc[i][7] + e[7];
    const size_t idx = (size_t)n * HIDN + colb;
    float2 cold = *(const float2*)(c + idx);
    float si0 = 1.f / (1.f + expf(-gi0));
    float sf0 = 1.f / (1.f + expf(-gf0));
    float tg0 = tanhf(gg0);
    float so0 = 1.f / (1.f + expf(-go0));
    float cn0 = sf0 * cold.x + si0 * tg0;
    float hn0 = so0 * tanhf(cn0);
    float si1 = 1.f / (1.f + expf(-gi1));
    float sf1 = 1.f / (1.f + expf(-gf1));
    float tg1 = tanhf(gg1);
    float so1 = 1.f / (1.f + expf(-go1));
    float cn1 = sf1 * cold.y + si1 * tg1;
    float hn1 = so1 * tanhf(cn1);
    *(float2*)(c + idx) = make_float2(cn0, cn1);
    *(float2*)(h + idx) = make_float2(hn0, hn1);
  }
}

// ---------------- EW0i[v][jj*4+q] = (emb[v] @ W_ih0^T)[q*512+jj] + b_ih0 + b_hh0 ----------------
__global__ void build_ew0(const float* __restrict__ emb, const float* __restrict__ W_ih0,
                          const float* __restrict__ b_ih0, const float* __restrict__ b_hh0,
                          float* __restrict__ EW0i)
{
  int idx = blockIdx.x * 256 + threadIdx.x;  // 32*2048
  int vv = idx >> 11, j = idx & 2047;        // j = gate-major index (q*512 + jj)
  float s = b_ih0[j] + b_hh0[j];
#pragma unroll
  for (int e = 0; e < 32; ++e)
    s = fmaf(emb[vv * 32 + e], W_ih0[(size_t)j * 32 + e], s);
  EW0i[(size_t)vv * 2048 + (size_t)(j & 511) * 4 + (j >> 9)] = s;
}

__global__ void build_bias1i(const float* __restrict__ a, const float* __restrict__ b,
                             float* __restrict__ o) {
  int j = blockIdx.x * 256 + threadIdx.x;    // 0..2047 gate-major
  o[(size_t)(j & 511) * 4 + (j >> 9)] = a[j] + b[j];
}

// init: token/length state, out col0, and the t=0 active list (order-free)
__global__ void init_state(const int* __restrict__ prevs, int* __restrict__ tok,
                           int* __restrict__ lengths, int* __restrict__ out,
                           int* __restrict__ list, int* __restrict__ cnt)
{
  int n = blockIdx.x * 256 + threadIdx.x;
  if (n < NROWS) {
    int p = prevs[n];
    tok[n] = p;
    lengths[n] = 0;
    out[(size_t)n * (TSTEPS + 1)] = p;
    if (p != EOS_TOK) {
      int pos = atomicAdd(&cnt[0], 1);
      list[pos] = n;
    }
  }
}

// ---------------- logits + gumbel + argmax + state update + next-list append ----------------
// Only active rows are dispatched (b < cnt[t]); rows launched here always have
// is_end == 0, so the PAD/freeze branch is gone (PAD handled by d_out pre-fill).
__global__ __launch_bounds__(64) void sample_step(
    const float* __restrict__ h1, const float* __restrict__ W_out,
    const float* __restrict__ b_out,
    int* __restrict__ tok, int* __restrict__ lengths,
    int* __restrict__ out, int* __restrict__ list, int* __restrict__ cnt,
    unsigned key0, unsigned key1, int t)
{
  const int nact = cnt[t];
  const int b = blockIdx.x;
  if (b >= nact) return;
  const int n = list[t * NROWS + b];

  __shared__ float hrow[HIDN];
  const int lane = threadIdx.x;
  {
    const float4* src = reinterpret_cast<const float4*>(h1 + (size_t)n * HIDN);
    float4* dst = reinterpret_cast<float4*>(hrow);
    dst[lane] = src[lane];
    dst[lane + 64] = src[lane + 64];
  }
  __syncthreads();
  const int v = lane & 31, half = lane >> 5;
  const float* wp = W_out + (size_t)v * HIDN + half * 256;
  const float* hh = hrow + half * 256;
  float dot = 0.f;
#pragma unroll
  for (int k = 0; k < 256; k += 4) {
    float4 wv = *reinterpret_cast<const float4*>(wp + k);
    float4 hv = *reinterpret_cast<const float4*>(hh + k);
    dot = fmaf(wv.x, hv.x, dot);
    dot = fmaf(wv.y, hv.y, dot);
    dot = fmaf(wv.z, hv.z, dot);
    dot = fmaf(wv.w, hv.w, dot);
  }
  dot += __shfl_xor(dot, 32);
  const float logit = dot + b_out[v];

  const unsigned iflat = (unsigned)(n * 32 + v);
  unsigned r0, r1, bits;
#if RNG_VARIANT == 1
  tf2x32(key0, key1, 0u, iflat, r0, r1);
  bits = r0 ^ r1;
#elif RNG_VARIANT == 2
  if (iflat < 65536u) { tf2x32(key0, key1, iflat, iflat + 65536u, r0, r1); bits = r0; }
  else                { tf2x32(key0, key1, iflat - 65536u, iflat, r0, r1); bits = r1; }
#else
  tf2x32(key0, key1, 0u, iflat, r0, r1);
  bits = r1;
#endif
  float f = __uint_as_float((bits >> 9) | 0x3f800000u) - 1.0f;
  float u = fmaxf(f, 1.1754943508222875e-38f);
  float t1 = -(float)log((double)u);
  float g  = -(float)log((double)t1);
  float s = g + logit;

  float bs = s; int bi = v;
#pragma unroll
  for (int off = 16; off >= 1; off >>= 1) {
    float os = __shfl_xor(bs, off);
    int   oi = __shfl_xor(bi, off);
    if (os > bs || (os == bs && oi < bi)) { bs = os; bi = oi; }
  }
  if (lane == 0) {
    const int cur = bi;                       // is_end was 0 for every launched row
    lengths[n] = lengths[n] + 1;
    tok[n] = cur;
    out[(size_t)n * (TSTEPS + 1) + t + 1] = cur;
    if (cur != EOS_TOK) {
      int pos = atomicAdd(&cnt[t + 1], 1);
      list[(t + 1) * NROWS + pos] = n;
    }
  }
}

__global__ void final_lengths(const int* __restrict__ lengths, int* __restrict__ out)
{
  int n = blockIdx.x * 256 + threadIdx.x;
  if (n < NROWS) out[(size_t)NROWS * (TSTEPS + 1) + n] = lengths[n] + 1;
}

// ---------------- host ----------------
extern "C" void kernel_launch(void* const* d_in, const int* in_sizes, int n_in,
                              void* d_out, int out_size, void* d_ws, size_t ws_size,
                              hipStream_t stream)
{
  const int*   prevs = (const int*)d_in[0];
  const float* emb   = (const float*)d_in[1];
  const float* W_ih0 = (const float*)d_in[2];
  const float* W_hh0 = (const float*)d_in[3];
  const float* b_ih0 = (const float*)d_in[4];
  const float* b_hh0 = (const float*)d_in[5];
  const float* W_ih1 = (const float*)d_in[6];
  const float* W_hh1 = (const float*)d_in[7];
  const float* b_ih1 = (const float*)d_in[8];
  const float* b_hh1 = (const float*)d_in[9];
  const float* W_out = (const float*)d_in[10];
  const float* b_out = (const float*)d_in[11];

  const size_t S = (size_t)NROWS * HIDN;
  float* h0a   = (float*)d_ws;      // zeroed (t=0 read)
  float* h1a   = h0a + S;           // zeroed
  float* cl0   = h1a + S;           // zeroed
  float* cl1   = cl0 + S;           // zeroed
  float* h0b   = cl1 + S;
  float* h1b   = h0b + S;
  float* EW0i  = h1b + S;           // 32*2048 interleaved
  float* bias1i = EW0i + (size_t)VOC * 2048;  // 2048 interleaved
  int* tok     = (int*)(bias1i + 2048);
  int* lengths = tok + NROWS;
  int* list    = lengths + NROWS;             // (TSTEPS+1) x NROWS
  int* cnt     = list + (TSTEPS + 1) * NROWS; // TSTEPS+1 counters
  int* outp    = (int*)d_out;

  hipMemsetAsync(h0a, 0, 4 * S * sizeof(float), stream);
  hipMemsetAsync(cnt, 0, (TSTEPS + 1) * sizeof(int), stream);
  hipMemsetAsync(outp, 0, (size_t)out_size * sizeof(int), stream);  // PAD=0 pre-fill
  init_state<<<NROWS / 256, 256, 0, stream>>>(prevs, tok, lengths, outp, list, cnt);
  build_ew0<<<VOC * 2048 / 256, 256, 0, stream>>>(emb, W_ih0, b_ih0, b_hh0, EW0i);
  build_bias1i<<<2048 / 256, 256, 0, stream>>>(b_ih1, b_hh1, bias1i);

  unsigned keys[TSTEPS][2];
  for (int t = 0; t < TSTEPS; ++t) {
    unsigned o0, o1;
    tf2x32(0u, 7u, 0u, (unsigned)t, o0, o1);
    keys[t][0] = o0; keys[t][1] = o1;
  }

  dim3 ggrid(HIDN / JJT, NROWS / BM);   // (16, 32) = 512 blocks (late blocks exit on n_active)
  for (int t = 0; t < TSTEPS; ++t) {
    float* h0rd = (t & 1) ? h0b : h0a;
    float* h0wr = (t & 1) ? h0a : h0b;
    float* h1rd = (t & 1) ? h1b : h1a;
    float* h1wr = (t & 1) ? h1a : h1b;
    lstm_fused<1, true><<<ggrid, 256, 0, stream>>>(
        h0rd, W_hh0, nullptr, nullptr, EW0i, tok, list, cnt, t, h0wr, cl0);
    lstm_fused<2, false><<<ggrid, 256, 0, stream>>>(
        h0wr, W_ih1, h1rd, W_hh1, bias1i, nullptr, list, cnt, t, h1wr, cl1);
    sample_step<<<NROWS, 64, 0, stream>>>(h1wr, W_out, b_out, tok, lengths, outp,
                                          list, cnt, keys[t][0], keys[t][1], t);
  }
  final_lengths<<<NROWS / 256, 256, 0, stream>>>(lengths, outp);
}